// Round 11
// baseline (185.284 us; speedup 1.0000x reference)
//
#include <hip/hip_runtime.h>
#include <hip/hip_bf16.h>

#define NROWS 32768
#define KCODES 8192
#define DDIM 128
#define TT 2048
#define ETOT 4194304  // 16*128*2048

typedef __attribute__((ext_vector_type(8))) _Float16 f16x8;
typedef __attribute__((ext_vector_type(4))) float f32x4;

// pack: (v & ~0x1FFF) | p, p in [0,8191] -> single v_and_or_b32.
// float compare then orders by (truncated value, then LOWER code first).
__device__ __forceinline__ float pk(float v, int p) {
    return __int_as_float((__float_as_int(v) & 0xFFFFE000) | p);
}

__device__ __forceinline__ void async16(char* lds_uniform, const char* g_perlane) {
    __builtin_amdgcn_global_load_lds(
        (const __attribute__((address_space(1))) unsigned int*)g_perlane,
        (__attribute__((address_space(3))) unsigned int*)lds_uniform,
        16, 0, 0);
}

// ---------------------------------------------------------------------------
// k1: normalize codebook rows, fp32 -> fp16, store in MFMA A-fragment order
//     per 16-code tile (4KB each): k_main staging stays linear, reads clean.
// code w: tile16=w>>4, c=w&15 ; dim d: ks=d>>5, kq=(d>>3)&3, dr=d&7
// elem off = tile16*2048 + ks*512 + (kq*16 + c)*8 + dr
// ---------------------------------------------------------------------------
__global__ void k_en_prep(const float* __restrict__ cb,
                          _Float16* __restrict__ eh) {
    int w = (blockIdx.x * blockDim.x + threadIdx.x) >> 6;  // code id
    int l = threadIdx.x & 63;
    if (w >= KCODES) return;
    const float* row = cb + (long)w * DDIM;
    float v0 = row[l], v1 = row[l + 64];
    float ss = v0 * v0 + v1 * v1;
#pragma unroll
    for (int s = 1; s < 64; s <<= 1) ss += __shfl_xor(ss, s, 64);
    float inv = 1.0f / fmaxf(sqrtf(ss), 1e-12f);
    int tile = w >> 4, c = w & 15;
#pragma unroll
    for (int e = 0; e < 2; e++) {
        int d = l + e * 64;
        float v = (e ? v1 : v0) * inv;
        int ks = d >> 5, kq = (d >> 3) & 3, dr = d & 7;
        long off = (long)tile * 2048 + ks * 512 + (kq * 16 + c) * 8 + dr;
        eh[off] = (_Float16)v;
    }
}

// ---------------------------------------------------------------------------
// k2: transpose inputs [B,D,T] -> xh [N=B*T, D] row-major fp16.
// ---------------------------------------------------------------------------
__global__ void k_x_prep(const float* __restrict__ in,
                         _Float16* __restrict__ xh) {
    __shared__ float tb[64][65];
    int bid = blockIdx.x;
    int tt0 = (bid & 31) * 64;
    int dd0 = ((bid >> 5) & 1) * 64;
    int b = bid >> 6;
    const float* base = in + (long)b * DDIM * TT;
    int tl = threadIdx.x & 63;
    int dg = threadIdx.x >> 6;
#pragma unroll
    for (int i = 0; i < 16; i++) {
        int dd = dg + i * 4;
        tb[dd][tl] = base[(long)(dd0 + dd) * TT + tt0 + tl];
    }
    __syncthreads();
    int dl = threadIdx.x & 63;
    int tg = threadIdx.x >> 6;
#pragma unroll
    for (int i = 0; i < 16; i++) {
        int t = tg + i * 4;
        long n = (long)b * TT + tt0 + t;
        xh[n * DDIM + dd0 + dl] = (_Float16)tb[dl][t];
    }
}

// ---------------------------------------------------------------------------
// k3 v11: CODE-SPLIT grid for occupancy. 1024 blocks x 256 thr (4 waves);
// block (rb,half) = 64 xrows x 4096 codes. Wave w owns a private 1024-code
// stream (64 tiles x 16 codes), double-buffered in its 8KB LDS slice via
// global_load_lds + counted vmcnt, NO main-loop barriers. 4 blocks/CU x
// 4 waves = 4 waves/SIMD (fixes r9/r10's grid-capped 2/SIMD). Per tile:
// 4 async16 + 4 ds_read_b128 + 16 MFMA (chains start from zero const) +
// 4-nf packed selection. Each block writes its half's top-4 -> cand[n][8].
// ---------------------------------------------------------------------------
__global__ __launch_bounds__(256, 4) void k_main(const _Float16* __restrict__ xh,
                                                 const _Float16* __restrict__ eh,
                                                 int* __restrict__ cand) {
    extern __shared__ char lds[];
    const int tid = threadIdx.x;
    const int l = tid & 63;
    const int w = tid >> 6;          // 0..3
    const int half = blockIdx.x & 1; // code half: [half*4096, half*4096+4096)
    const int col = l & 15, kq = l >> 4;
    const long rbase = (long)(blockIdx.x >> 1) * 64;

    // B-operand x-fragments, loaded once: 4 nf x 4 ks = 64 regs
    f16x8 bx[4][4];
#pragma unroll
    for (int nf = 0; nf < 4; nf++) {
        long n = rbase + nf * 16 + col;
#pragma unroll
        for (int ks = 0; ks < 4; ks++)
            bx[nf][ks] = *(const f16x8*)(xh + n * DDIM + ks * 32 + kq * 8);
    }

    const float NEG = __int_as_float(0xFF800000);  // -inf (payload bits 0)
    const f32x4 Z = {0.f, 0.f, 0.f, 0.f};          // shared C-in for chain starts
    float t1[4], t2[4], t3[4], u1[4];
#pragma unroll
    for (int i = 0; i < 4; i++) { t1[i] = t2[i] = t3[i] = u1[i] = NEG; }

    // wave's code base: half*4096 + w*1024 ; payload = 8191 - code
    int P = 8191 - (half * 4096 + w * 1024 + kq * 4);

    const char* gsrc = (const char*)eh + (long)half * 1048576 + (long)w * 262144 + l * 16;
    char* lbase = lds + w * 8192;        // private 2 x 4KB double buffer

    // prologue: stage tile 0 into buf 0
#pragma unroll
    for (int ks = 0; ks < 4; ks++)
        async16(lbase + ks * 1024, gsrc + ks * 1024);

    for (int t = 0; t < 64; ++t) {
        if (t < 63) {
            const char* gs = gsrc + (t + 1) * 4096;
            char* nb = lbase + ((t + 1) & 1) * 4096;
#pragma unroll
            for (int ks = 0; ks < 4; ks++)
                async16(nb + ks * 1024, gs + ks * 1024);
            asm volatile("s_waitcnt vmcnt(4)" ::: "memory");  // tile t landed
        } else {
            asm volatile("s_waitcnt vmcnt(0)" ::: "memory");  // final drain
        }

        const char* buf = lbase + (t & 1) * 4096;
        f16x8 ah[4];
#pragma unroll
        for (int ks = 0; ks < 4; ks++)
            ah[ks] = *(const f16x8*)(buf + ks * 1024 + l * 16);

        __builtin_amdgcn_s_setprio(1);
        f32x4 acc[4];
#pragma unroll
        for (int nf = 0; nf < 4; nf++) {
            f32x4 a = __builtin_amdgcn_mfma_f32_16x16x32_f16(ah[0], bx[nf][0], Z, 0, 0, 0);
            a = __builtin_amdgcn_mfma_f32_16x16x32_f16(ah[1], bx[nf][1], a, 0, 0, 0);
            a = __builtin_amdgcn_mfma_f32_16x16x32_f16(ah[2], bx[nf][2], a, 0, 0, 0);
            acc[nf] = __builtin_amdgcn_mfma_f32_16x16x32_f16(ah[3], bx[nf][3], a, 0, 0, 0);
        }
        __builtin_amdgcn_s_setprio(0);

        // index-free selection on packed floats
#pragma unroll
        for (int nf = 0; nf < 4; nf++) {
            f32x4 a = acc[nf];
            float s0 = pk(a[0], P),     s1 = pk(a[1], P - 1);
            float s2 = pk(a[2], P - 2), s3 = pk(a[3], P - 3);
            float h01 = fmaxf(s0, s1), l01 = fminf(s0, s1);
            float h23 = fmaxf(s2, s3), l23 = fminf(s2, s3);
            float m1 = fmaxf(h01, h23);                          // quad max
            float m2 = fmaxf(fminf(h01, h23), fmaxf(l01, l23));  // quad 2nd
            float n1 = fminf(t1[nf], m1); t1[nf] = fmaxf(t1[nf], m1);
            float n2 = fminf(t2[nf], n1); t2[nf] = fmaxf(t2[nf], n1);
            t3[nf] = fmaxf(t3[nf], n2);
            u1[nf] = fmaxf(u1[nf], m2);
        }
        P -= 16;
    }

    __syncthreads();  // waves done streaming; reuse LDS for merge
    float* mrg = (float*)lds;  // [64 rows][68] = 17.4KB
#pragma unroll
    for (int nf = 0; nf < 4; nf++) {
        int row = nf * 16 + col;
        int e = w * 16 + kq * 4;
        mrg[row * 68 + e + 0] = t1[nf];
        mrg[row * 68 + e + 1] = t2[nf];
        mrg[row * 68 + e + 2] = t3[nf];
        mrg[row * 68 + e + 3] = u1[nf];
    }
    __syncthreads();
    if (tid < 64) {
        float s1 = NEG, s2 = NEG, s3 = NEG, s4 = NEG;
#pragma unroll 8
        for (int e = 0; e < 64; e++) {
            float v = mrg[tid * 68 + e];
            float a1 = fminf(s1, v); s1 = fmaxf(s1, v);
            float a2 = fminf(s2, a1); s2 = fmaxf(s2, a1);
            float a3 = fminf(s3, a2); s3 = fmaxf(s3, a2);
            s4 = fmaxf(s4, a3);
        }
        long n = rbase + tid;
        int* cp = cand + n * 8 + half * 4;
        cp[0] = 8191 - (__float_as_int(s1) & 0x1FFF);
        cp[1] = 8191 - (__float_as_int(s2) & 0x1FFF);
        cp[2] = 8191 - (__float_as_int(s3) & 0x1FFF);
        cp[3] = 8191 - (__float_as_int(s4) & 0x1FFF);
    }
}

// ---------------------------------------------------------------------------
// k4 v3 (FUSED refine + out + loss): thread-per-row. fp64 exact scores for
// the 8 candidates (4 per code-half), winner -> idx float; then stream the
// winner row: out = x + (q - x) in [B,D,T] order + fp64 diff^2 partials.
// 128 blocks x 256 thr = 32768 threads, 1:1 rows.
// ---------------------------------------------------------------------------
__global__ void k_refine_out(const float* __restrict__ in, const float* __restrict__ cb,
                             const int* __restrict__ cand, float* __restrict__ out,
                             float* __restrict__ idx_f, double* __restrict__ part) {
    __shared__ double sd[256];
    int n = blockIdx.x * blockDim.x + threadIdx.x;   // NROWS == grid*block exactly
    int b = n >> 11, t = n & 2047;
    const float* xb = in + (long)b * DDIM * TT + t;

    int c[8];
#pragma unroll
    for (int k = 0; k < 8; k++) c[k] = cand[n * 8 + k];

    double dot[8], nrm[8];
#pragma unroll
    for (int k = 0; k < 8; k++) { dot[k] = 0.0; nrm[k] = 0.0; }

    for (int d4 = 0; d4 < 32; d4++) {
        float4 q[8];
#pragma unroll
        for (int k = 0; k < 8; k++)
            q[k] = ((const float4*)(cb + (long)c[k] * DDIM))[d4];
#pragma unroll
        for (int j = 0; j < 4; j++) {
            double xd = (double)xb[(long)(d4 * 4 + j) * TT];
#pragma unroll
            for (int k = 0; k < 8; k++) {
                double f = (double)((const float*)&q[k])[j];
                dot[k] += xd * f;
                nrm[k] += f * f;
            }
        }
    }

    double best = -1e300;
    int bi = 0x7fffffff;
#pragma unroll
    for (int k = 0; k < 8; k++) {
        double sv = dot[k] / fmax(sqrt(nrm[k]), 1e-12);
        if (sv > best || (sv == best && c[k] < bi)) { best = sv; bi = c[k]; }
    }
    idx_f[n] = (float)bi;

    // pass 2: winner row -> out + loss partials
    const float4* e = (const float4*)(cb + (long)bi * DDIM);
    float* ob = out + (long)b * DDIM * TT + t;
    double acc = 0.0;
    for (int d4 = 0; d4 < 32; d4++) {
        float4 qv = e[d4];
#pragma unroll
        for (int j = 0; j < 4; j++) {
            long doff = (long)(d4 * 4 + j) * TT;
            float xv = xb[doff];
            float diff = ((const float*)&qv)[j] - xv;
            ob[doff] = xv + diff;
            acc += (double)diff * (double)diff;
        }
    }
    sd[threadIdx.x] = acc;
    __syncthreads();
    for (int s = 128; s > 0; s >>= 1) {
        if (threadIdx.x < s) sd[threadIdx.x] += sd[threadIdx.x + s];
        __syncthreads();
    }
    if (threadIdx.x == 0) part[blockIdx.x] = sd[0];
}

__global__ void k_loss_final(const double* __restrict__ part, int np,
                             float* __restrict__ loss) {
    __shared__ double sd[256];
    double a = 0.0;
    for (int i = threadIdx.x; i < np; i += 256) a += part[i];
    sd[threadIdx.x] = a;
    __syncthreads();
    for (int s = 128; s > 0; s >>= 1) {
        if (threadIdx.x < s) sd[threadIdx.x] += sd[threadIdx.x + s];
        __syncthreads();
    }
    if (threadIdx.x == 0) {
        float m = (float)(sd[0] / (double)ETOT);
        loss[0] = m + 0.02f * m;
    }
}

// ---------------------------------------------------------------------------
extern "C" void kernel_launch(void* const* d_in, const int* in_sizes, int n_in,
                              void* d_out, int out_size, void* d_ws, size_t ws_size,
                              hipStream_t stream) {
    const float* inputs = (const float*)d_in[0];   // [16,128,2048] fp32
    const float* cb     = (const float*)d_in[1];   // [8192,128]    fp32
    float* outf = (float*)d_out;                   // [loss | out(B,D,T) | idx]

    char* ws = (char*)d_ws;
    _Float16* xh = (_Float16*)ws; ws += (long)NROWS * DDIM * 2;
    _Float16* eh = (_Float16*)ws; ws += (long)KCODES * DDIM * 2;
    int* cand    = (int*)ws;      ws += (long)NROWS * 8 * 4;
    double* part = (double*)ws;   ws += 128 * 8;

    k_en_prep<<<dim3(2048), dim3(256), 0, stream>>>(cb, eh);
    k_x_prep<<<dim3(1024), dim3(256), 0, stream>>>(inputs, xh);
    k_main<<<dim3(1024), dim3(256), 32768, stream>>>(xh, eh, cand);
    k_refine_out<<<dim3(128), dim3(256), 0, stream>>>(inputs, cb, cand, outf + 1,
                                                      outf + 1 + (long)ETOT, part);
    k_loss_final<<<dim3(1), dim3(256), 0, stream>>>(part, 128, outf);
}

// Round 12
// 166.687 us; speedup vs baseline: 1.1116x; 1.1116x over previous
//
#include <hip/hip_runtime.h>
#include <hip/hip_bf16.h>

#define NROWS 32768
#define KCODES 8192
#define DDIM 128
#define TT 2048
#define ETOT 4194304  // 16*128*2048

typedef __attribute__((ext_vector_type(8))) _Float16 f16x8;
typedef __attribute__((ext_vector_type(4))) float f32x4;

// pack: (v & ~0x1FFF) | p, p in [0,8191] -> single v_and_or_b32.
// float compare then orders by (truncated value, then LOWER code first).
__device__ __forceinline__ float pk(float v, int p) {
    return __int_as_float((__float_as_int(v) & 0xFFFFE000) | p);
}

__device__ __forceinline__ void async16(char* lds_uniform, const char* g_perlane) {
    __builtin_amdgcn_global_load_lds(
        (const __attribute__((address_space(1))) unsigned int*)g_perlane,
        (__attribute__((address_space(3))) unsigned int*)lds_uniform,
        16, 0, 0);
}

// ---------------------------------------------------------------------------
// k1: normalize codebook rows, fp32 -> fp16, MFMA A-fragment order per
//     16-code tile (4KB each): staging linear, ds_read_b128 conflict-free.
// code w: tile16=w>>4, c=w&15 ; dim d: ks=d>>5, kq=(d>>3)&3, dr=d&7
// elem off = tile16*2048 + ks*512 + (kq*16 + c)*8 + dr
// ---------------------------------------------------------------------------
__global__ void k_en_prep(const float* __restrict__ cb,
                          _Float16* __restrict__ eh) {
    int w = (blockIdx.x * blockDim.x + threadIdx.x) >> 6;  // code id
    int l = threadIdx.x & 63;
    if (w >= KCODES) return;
    const float* row = cb + (long)w * DDIM;
    float v0 = row[l], v1 = row[l + 64];
    float ss = v0 * v0 + v1 * v1;
#pragma unroll
    for (int s = 1; s < 64; s <<= 1) ss += __shfl_xor(ss, s, 64);
    float inv = 1.0f / fmaxf(sqrtf(ss), 1e-12f);
    int tile = w >> 4, c = w & 15;
#pragma unroll
    for (int e = 0; e < 2; e++) {
        int d = l + e * 64;
        float v = (e ? v1 : v0) * inv;
        int ks = d >> 5, kq = (d >> 3) & 3, dr = d & 7;
        long off = (long)tile * 2048 + ks * 512 + (kq * 16 + c) * 8 + dr;
        eh[off] = (_Float16)v;
    }
}

// ---------------------------------------------------------------------------
// k2: transpose inputs [B,D,T] -> xh [N=B*T, D] row-major fp16.
// ---------------------------------------------------------------------------
__global__ void k_x_prep(const float* __restrict__ in,
                         _Float16* __restrict__ xh) {
    __shared__ float tb[64][65];
    int bid = blockIdx.x;
    int tt0 = (bid & 31) * 64;
    int dd0 = ((bid >> 5) & 1) * 64;
    int b = bid >> 6;
    const float* base = in + (long)b * DDIM * TT;
    int tl = threadIdx.x & 63;
    int dg = threadIdx.x >> 6;
#pragma unroll
    for (int i = 0; i < 16; i++) {
        int dd = dg + i * 4;
        tb[dd][tl] = base[(long)(dd0 + dd) * TT + tt0 + tl];
    }
    __syncthreads();
    int dl = threadIdx.x & 63;
    int tg = threadIdx.x >> 6;
#pragma unroll
    for (int i = 0; i < 16; i++) {
        int t = tg + i * 4;
        long n = (long)b * TT + tt0 + t;
        xh[n * DDIM + dd0 + dl] = (_Float16)tb[dl][t];
    }
}

// ---------------------------------------------------------------------------
// k3 v12: SHARED staging (4x LDS reuse). 1024 blocks x 256 thr (4 waves);
// block (rb,e) = 256 xrows x 1024 codes (eighth e). Waves split ROWS (wave w
// = rows w*64..w*64+63, nf=4), all 4 waves consume the SAME staged 16-code
// tile: per slot 4KB write + 16KB read feeds 64 MFMAs (r11's private streams
// fed 16 -> LDS-BW-bound at 134 B/cyc). Triple-buffered 12KB, counted
// vmcnt(1)+lgkmcnt(0)+s_barrier per tile (r2-proven skeleton, stage rides
// across barrier). Inner selection identical to r10/r11. Per-block output:
// top-2 of eighth per row -> cand[n][16].
// ---------------------------------------------------------------------------
__global__ __launch_bounds__(256, 4) void k_main(const _Float16* __restrict__ xh,
                                                 const _Float16* __restrict__ eh,
                                                 int* __restrict__ cand) {
    extern __shared__ char lds[];
    const int tid = threadIdx.x;
    const int l = tid & 63;
    const int w = tid >> 6;          // 0..3 : wave id = row group of 64
    const int e8 = blockIdx.x & 7;   // code eighth: [e8*1024, e8*1024+1024)
    const int rb = blockIdx.x >> 3;
    const int col = l & 15, kq = l >> 4;
    const long rbase = (long)rb * 256;

    // B-operand x-fragments, loaded once: 4 nf x 4 ks (wave's own 64 rows)
    f16x8 bx[4][4];
#pragma unroll
    for (int nf = 0; nf < 4; nf++) {
        long n = rbase + w * 64 + nf * 16 + col;
#pragma unroll
        for (int ks = 0; ks < 4; ks++)
            bx[nf][ks] = *(const f16x8*)(xh + n * DDIM + ks * 32 + kq * 8);
    }

    const float NEG = __int_as_float(0xFF800000);  // -inf (payload bits 0)
    const f32x4 Z = {0.f, 0.f, 0.f, 0.f};
    float t1[4], t2[4], t3[4], u1[4];
#pragma unroll
    for (int i = 0; i < 4; i++) { t1[i] = t2[i] = t3[i] = u1[i] = NEG; }

    // code = e8*1024 + t*16 + kq*4 + j ; payload = 8191 - code
    int P = 8191 - (e8 * 1024 + kq * 4);

    // staging: per tile 4KB; each thread copies 16B. per-wave LDS base
    // (wave-uniform) = buf + w*1024; global src = + w*1024 + l*16.
    const char* gsrc = (const char*)eh + (long)e8 * 262144 + w * 1024 + l * 16;
    char* b0 = lds;
    char* b1 = lds + 4096;
    char* b2 = lds + 8192;

    // prologue: stage tiles 0,1
    async16(b0 + w * 1024, gsrc);
    async16(b1 + w * 1024, gsrc + 4096);

    for (int t = 0; t < 64; ++t) {
        if (t < 62) {
            // own stage(t) landed (stage(t+1) stays in flight); own ds_reads
            // of t-1 done; then all 4 waves rendezvous -> tile t fully ready.
            asm volatile("s_waitcnt vmcnt(1) lgkmcnt(0)\n\ts_barrier" ::: "memory");
            async16(b2 + w * 1024, gsrc + (t + 2) * 4096);
        } else if (t == 62) {
            asm volatile("s_waitcnt vmcnt(1) lgkmcnt(0)\n\ts_barrier" ::: "memory");
        } else {
            asm volatile("s_waitcnt vmcnt(0) lgkmcnt(0)\n\ts_barrier" ::: "memory");
        }

        f16x8 ah[4];
#pragma unroll
        for (int ks = 0; ks < 4; ks++)
            ah[ks] = *(const f16x8*)(b0 + ks * 1024 + l * 16);

        __builtin_amdgcn_s_setprio(1);
        f32x4 acc[4];
#pragma unroll
        for (int nf = 0; nf < 4; nf++) {
            f32x4 a = __builtin_amdgcn_mfma_f32_16x16x32_f16(ah[0], bx[nf][0], Z, 0, 0, 0);
            a = __builtin_amdgcn_mfma_f32_16x16x32_f16(ah[1], bx[nf][1], a, 0, 0, 0);
            a = __builtin_amdgcn_mfma_f32_16x16x32_f16(ah[2], bx[nf][2], a, 0, 0, 0);
            acc[nf] = __builtin_amdgcn_mfma_f32_16x16x32_f16(ah[3], bx[nf][3], a, 0, 0, 0);
        }
        __builtin_amdgcn_s_setprio(0);

        // index-free selection on packed floats (identical to r10/r11)
#pragma unroll
        for (int nf = 0; nf < 4; nf++) {
            f32x4 a = acc[nf];
            float s0 = pk(a[0], P),     s1 = pk(a[1], P - 1);
            float s2 = pk(a[2], P - 2), s3 = pk(a[3], P - 3);
            float h01 = fmaxf(s0, s1), l01 = fminf(s0, s1);
            float h23 = fmaxf(s2, s3), l23 = fminf(s2, s3);
            float m1 = fmaxf(h01, h23);                          // quad max
            float m2 = fmaxf(fminf(h01, h23), fmaxf(l01, l23));  // quad 2nd
            float n1 = fminf(t1[nf], m1); t1[nf] = fmaxf(t1[nf], m1);
            float n2 = fminf(t2[nf], n1); t2[nf] = fmaxf(t2[nf], n1);
            t3[nf] = fmaxf(t3[nf], n2);
            u1[nf] = fmaxf(u1[nf], m2);
        }
        P -= 16;

        char* tmp = b0; b0 = b1; b1 = b2; b2 = tmp;
    }

    // merge: 16 entries per row (4 kq-lanes x {t1,t2,t3,u1}) -> top-2/eighth
    float* mrg = (float*)(lds + 12288);  // [256 rows][17]
#pragma unroll
    for (int nf = 0; nf < 4; nf++) {
        int row = w * 64 + nf * 16 + col;
        int e = kq * 4;
        mrg[row * 17 + e + 0] = t1[nf];
        mrg[row * 17 + e + 1] = t2[nf];
        mrg[row * 17 + e + 2] = t3[nf];
        mrg[row * 17 + e + 3] = u1[nf];
    }
    __syncthreads();
    {
        float s1 = NEG, s2 = NEG;
#pragma unroll 4
        for (int e = 0; e < 16; e++) {
            float v = mrg[tid * 17 + e];
            float a1 = fminf(s1, v); s1 = fmaxf(s1, v);
            s2 = fmaxf(s2, a1);
        }
        long n = rbase + tid;
        int* cp = cand + n * 16 + e8 * 2;
        cp[0] = 8191 - (__float_as_int(s1) & 0x1FFF);
        cp[1] = 8191 - (__float_as_int(s2) & 0x1FFF);
    }
}

// ---------------------------------------------------------------------------
// k4 v4: lane-per-(row,candidate) fp64 refine. 2048 blocks x 256 thr =
// 524288 threads = 16 lanes/row (one per candidate), 16-lane shuffle reduce
// with exact (score, lower-code) ordering. Fixes r11's 2-waves/CU latency.
// ---------------------------------------------------------------------------
__global__ void k_refine16(const float* __restrict__ in, const float* __restrict__ cb,
                           const int* __restrict__ cand, int* __restrict__ idx_out,
                           float* __restrict__ idx_f) {
    int g = blockIdx.x * blockDim.x + threadIdx.x;
    int n = g >> 4, k = g & 15;
    int b = n >> 11, t = n & 2047;
    const float* xb = in + (long)b * DDIM * TT + t;
    int c = cand[n * 16 + k];
    const float4* e = (const float4*)(cb + (long)c * DDIM);
    double dot = 0.0, nrm = 0.0;
    for (int d4 = 0; d4 < 32; d4++) {
        float4 q = e[d4];
#pragma unroll
        for (int j = 0; j < 4; j++) {
            double xd = (double)xb[(long)(d4 * 4 + j) * TT];
            double f = (double)((const float*)&q)[j];
            dot += xd * f;
            nrm += f * f;
        }
    }
    double sv = dot / fmax(sqrt(nrm), 1e-12);
#pragma unroll
    for (int s = 1; s < 16; s <<= 1) {
        double osv = __shfl_xor(sv, s, 64);
        int oc = __shfl_xor(c, s, 64);
        if (osv > sv || (osv == sv && oc < c)) { sv = osv; c = oc; }
    }
    if (k == 0) {
        idx_out[n] = c;
        idx_f[n] = (float)c;
    }
}

// ---------------------------------------------------------------------------
// k5: out = x + (q - x) in [B,D,T] order + fp64 partial sums of (q-x)^2.
// ---------------------------------------------------------------------------
__global__ void k_out_loss(const float* __restrict__ in, const float* __restrict__ cb,
                           const int* __restrict__ idx, float* __restrict__ out,
                           double* __restrict__ part) {
    __shared__ double sd[256];
    double acc = 0.0;
    for (long e = (long)blockIdx.x * blockDim.x + threadIdx.x; e < ETOT;
         e += (long)gridDim.x * blockDim.x) {
        long t = e & 2047;
        long d = (e >> 11) & 127;
        long b = e >> 18;
        float xv = in[e];
        int n = (int)((b << 11) | t);
        float qv = cb[(long)idx[n] * DDIM + d];
        float diff = qv - xv;
        out[e] = xv + diff;
        acc += (double)diff * (double)diff;
    }
    sd[threadIdx.x] = acc;
    __syncthreads();
    for (int s = 128; s > 0; s >>= 1) {
        if (threadIdx.x < s) sd[threadIdx.x] += sd[threadIdx.x + s];
        __syncthreads();
    }
    if (threadIdx.x == 0) part[blockIdx.x] = sd[0];
}

__global__ void k_loss_final(const double* __restrict__ part, int np,
                             float* __restrict__ loss) {
    __shared__ double sd[256];
    double a = 0.0;
    for (int i = threadIdx.x; i < np; i += 256) a += part[i];
    sd[threadIdx.x] = a;
    __syncthreads();
    for (int s = 128; s > 0; s >>= 1) {
        if (threadIdx.x < s) sd[threadIdx.x] += sd[threadIdx.x + s];
        __syncthreads();
    }
    if (threadIdx.x == 0) {
        float m = (float)(sd[0] / (double)ETOT);
        loss[0] = m + 0.02f * m;
    }
}

// ---------------------------------------------------------------------------
extern "C" void kernel_launch(void* const* d_in, const int* in_sizes, int n_in,
                              void* d_out, int out_size, void* d_ws, size_t ws_size,
                              hipStream_t stream) {
    const float* inputs = (const float*)d_in[0];   // [16,128,2048] fp32
    const float* cb     = (const float*)d_in[1];   // [8192,128]    fp32
    float* outf = (float*)d_out;                   // [loss | out(B,D,T) | idx]

    char* ws = (char*)d_ws;
    _Float16* xh = (_Float16*)ws; ws += (long)NROWS * DDIM * 2;
    _Float16* eh = (_Float16*)ws; ws += (long)KCODES * DDIM * 2;
    int* cand    = (int*)ws;      ws += (long)NROWS * 16 * 4;
    int* idx     = (int*)ws;      ws += (long)NROWS * 4;
    double* part = (double*)ws;   ws += 2048 * 8;

    k_en_prep<<<dim3(2048), dim3(256), 0, stream>>>(cb, eh);
    k_x_prep<<<dim3(1024), dim3(256), 0, stream>>>(inputs, xh);
    k_main<<<dim3(1024), dim3(256), 29696, stream>>>(xh, eh, cand);
    k_refine16<<<dim3(2048), dim3(256), 0, stream>>>(inputs, cb, cand, idx,
                                                     outf + 1 + (long)ETOT);
    k_out_loss<<<dim3(2048), dim3(256), 0, stream>>>(inputs, cb, idx, outf + 1, part);
    k_loss_final<<<dim3(1), dim3(256), 0, stream>>>(part, 2048, outf);
}